// Round 1
// 3087.005 us; speedup vs baseline: 2.2383x; 2.2383x over previous
//
#include <hip/hip_runtime.h>
#include <math.h>

#define NHEAD 16
#define DMODEL 1024
#define BATCH 2
#define QSCALE 0.125f

typedef __attribute__((ext_vector_type(8))) short bf16x8;
typedef __attribute__((ext_vector_type(4))) float f32x4;

__device__ inline unsigned short f2bf(float x) {
  unsigned int u = __float_as_uint(x);
  u += 0x7FFF + ((u >> 16) & 1);
  return (unsigned short)(u >> 16);
}
__device__ inline float bf2f(unsigned short h) {
  return __uint_as_float(((unsigned int)h) << 16);
}

// =====================================================================
// bf16 MFMA GEMM: C[M,N] = A @ B, A bf16 [M][K], Bt bf16 [Npad][K]
// (row n of Bt = column n of B). Tile 128x128, BK=64, 256 thr = 4 waves.
// MODE 0: +bias (fp32 out). MODE 1: (acc+bias)*QSCALE fp32.
// MODE 2: acc+bias+bf2f(R) fp32. MODE 3: wrel bf16 C[head][r][h].
// MODE 4: +bias, bf16 out.
// =====================================================================
template<int MODE>
__global__ __launch_bounds__(256) void gemm_bf16(
    const unsigned short* __restrict__ A, const unsigned short* __restrict__ Bt,
    const float* __restrict__ bias, const unsigned short* __restrict__ R,
    void* __restrict__ Cv, int M, int N, int K, int nrel)
{
  __shared__ unsigned short smem[32 * 512];  // A frags 0..15, B frags 16..31
  const int tid = threadIdx.x;
  const int lane = tid & 63, w = tid >> 6;
  const int mw = w >> 1, nw = w & 1;
  const int bm = blockIdx.x * 128, bn = blockIdx.y * 128;
  const int lm = lane & 15, lq = lane >> 4;
  float* Cf = (float*)Cv;
  unsigned short* Cb = (unsigned short*)Cv;

  f32x4 acc[4][4];
#pragma unroll
  for (int i = 0; i < 4; ++i)
#pragma unroll
    for (int j = 0; j < 4; ++j) acc[i][j] = (f32x4){0.f, 0.f, 0.f, 0.f};

  for (int k0 = 0; k0 < K; k0 += 64) {
#pragma unroll
    for (int f = w; f < 16; f += 4) {
      const int kb = f >> 3, mb = f & 7;
      const int gr = bm + mb * 16 + lm;
      const int gc = k0 + kb * 32 + lq * 8;
      const uint4 va = *(const uint4*)(A + (size_t)gr * K + gc);
      *(uint4*)(&smem[f * 512 + lane * 8]) = va;
      const int nr = bn + mb * 16 + lm;
      const uint4 vb = *(const uint4*)(Bt + (size_t)nr * K + gc);
      *(uint4*)(&smem[(16 + f) * 512 + lane * 8]) = vb;
    }
    __syncthreads();
#pragma unroll
    for (int kb = 0; kb < 2; ++kb) {
      bf16x8 af[4], bf[4];
#pragma unroll
      for (int i = 0; i < 4; ++i)
        af[i] = *(const bf16x8*)(&smem[(kb * 8 + mw * 4 + i) * 512 + lane * 8]);
#pragma unroll
      for (int j = 0; j < 4; ++j)
        bf[j] = *(const bf16x8*)(&smem[(16 + kb * 8 + nw * 4 + j) * 512 + lane * 8]);
#pragma unroll
      for (int i = 0; i < 4; ++i)
#pragma unroll
        for (int j = 0; j < 4; ++j)
          acc[i][j] = __builtin_amdgcn_mfma_f32_16x16x32_bf16(
              af[i], bf[j], acc[i][j], 0, 0, 0);
    }
    __syncthreads();
  }
#pragma unroll
  for (int i = 0; i < 4; ++i) {
#pragma unroll
    for (int j = 0; j < 4; ++j) {
      const int col = bn + nw * 64 + j * 16 + lm;
      if (col >= N) continue;
#pragma unroll
      for (int r = 0; r < 4; ++r) {
        const int row = bm + mw * 64 + i * 16 + lq * 4 + r;
        float vv = acc[i][j][r];
        if (MODE == 0) vv += bias[col];
        else if (MODE == 1) vv = (vv + bias[col]) * QSCALE;
        else if (MODE == 2) vv = vv + bias[col] + bf2f(R[(size_t)row * N + col]);
        else if (MODE == 4) vv += bias[col];
        if (MODE == 3)
          Cb[(((size_t)(row >> 6)) * nrel + col) * 64 + (row & 63)] = f2bf(vv);
        else if (MODE == 4)
          Cb[(size_t)row * N + col] = f2bf(vv);
        else
          Cf[(size_t)row * N + col] = vv;
      }
    }
  }
}

// =====================================================================
// transpose + fp32->bf16: in [1024][1024] fp32 -> out [1024][1024] bf16^T
// =====================================================================
__global__ __launch_bounds__(256) void tpose_k(
    const float* __restrict__ in, unsigned short* __restrict__ out)
{
  __shared__ float t[32][33];
  const int bi = blockIdx.x * 32, bj = blockIdx.y * 32;
  const int r = threadIdx.x >> 3, c4 = (threadIdx.x & 7) * 4;
  const float4 v = *(const float4*)(in + (size_t)(bi + r) * 1024 + bj + c4);
  t[r][c4] = v.x; t[r][c4 + 1] = v.y; t[r][c4 + 2] = v.z; t[r][c4 + 3] = v.w;
  __syncthreads();
  ushort4 o;
  o.x = f2bf(t[c4 + 0][r]); o.y = f2bf(t[c4 + 1][r]);
  o.z = f2bf(t[c4 + 2][r]); o.w = f2bf(t[c4 + 3][r]);
  *(ushort4*)(out + (size_t)(bj + r) * 1024 + bi + c4) = o;
}

// fp32 -> bf16 elementwise
__global__ void cvt_k(const float* __restrict__ in,
                      unsigned short* __restrict__ out, int n)
{
  const int i = blockIdx.x * 256 + threadIdx.x;
  if (i < n) out[i] = f2bf(in[i]);
}

// =====================================================================
// trig table (bf16, transposed): T[r][f] = sgn*sin(ang), T[r][f+512]=cos(ang)
// =====================================================================
__global__ void trig_fill(unsigned short* __restrict__ T, int rPad, int rmin,
                          int rstep, float sgn)
{
  const int idx = blockIdx.x * 256 + threadIdx.x;
  if (idx >= rPad * 512) return;
  const int r = idx >> 9, f = idx & 511;
  const float invf = expf((float)f * -(9.210340371976184f / 512.0f));
  const float ang = (float)(rmin + r * rstep) * invf;
  float s, c;
  sincosf(ang, &s, &c);
  T[(size_t)r * 1024 + f] = f2bf(sgn * s);
  T[(size_t)r * 1024 + f + 512] = f2bf(c);
}

// =====================================================================
// upsample (bf16)
// =====================================================================
__global__ void upsample_k(const unsigned short* __restrict__ h,
                           unsigned short* __restrict__ out, int L)
{
  const size_t idx = (size_t)blockIdx.x * 256 + threadIdx.x;
  const size_t total = (size_t)BATCH * 2 * L * DMODEL;
  if (idx >= total) return;
  const int d = (int)(idx & 1023);
  const int t2 = (int)((idx >> 10) % (size_t)(2 * L));
  const int b = (int)((idx >> 10) / (size_t)(2 * L));
  const unsigned short* hb = h + (size_t)b * L * DMODEL;
  float val;
  if ((t2 & 1) == 0) {
    val = bf2f(hb[(size_t)(t2 >> 1) * DMODEL + d]);
  } else {
    const int t = (t2 - 1) >> 1;
    const int prev = (t == 0) ? (L - 1) : (t - 1);
    val = 0.5f * (bf2f(hb[(size_t)t * DMODEL + d]) +
                  bf2f(hb[(size_t)prev * DMODEL + d]));
  }
  out[idx] = f2bf(val);
}

// =====================================================================
// LayerNorm over D=1024
// =====================================================================
template<bool BF16OUT>
__global__ __launch_bounds__(256) void ln_k(
    const float* __restrict__ x, const float* __restrict__ g,
    const float* __restrict__ b, void* __restrict__ outv)
{
  const int row = blockIdx.x;
  const int tid = threadIdx.x;
  const float* xr = x + (size_t)row * DMODEL;
  const float4 xv = *(const float4*)(xr + tid * 4);
  __shared__ float red[4];
  float s = xv.x + xv.y + xv.z + xv.w;
#pragma unroll
  for (int off = 32; off > 0; off >>= 1) s += __shfl_down(s, off, 64);
  if ((tid & 63) == 0) red[tid >> 6] = s;
  __syncthreads();
  const float mean = (red[0] + red[1] + red[2] + red[3]) * (1.f / 1024.f);
  const float dx = xv.x - mean, dy = xv.y - mean;
  const float dz = xv.z - mean, dw = xv.w - mean;
  float vs = dx * dx + dy * dy + dz * dz + dw * dw;
  __syncthreads();
#pragma unroll
  for (int off = 32; off > 0; off >>= 1) vs += __shfl_down(vs, off, 64);
  if ((tid & 63) == 0) red[tid >> 6] = vs;
  __syncthreads();
  const float var = (red[0] + red[1] + red[2] + red[3]) * (1.f / 1024.f);
  const float rstd = rsqrtf(var + 1e-9f);
  const float4 gv = *(const float4*)(g + tid * 4);
  const float4 bv = *(const float4*)(b + tid * 4);
  const float ox = dx * rstd * gv.x + bv.x;
  const float oy = dy * rstd * gv.y + bv.y;
  const float oz = dz * rstd * gv.z + bv.z;
  const float ow = dw * rstd * gv.w + bv.w;
  if (BF16OUT) {
    ushort4 o = {f2bf(ox), f2bf(oy), f2bf(oz), f2bf(ow)};
    *(ushort4*)((unsigned short*)outv + (size_t)row * DMODEL + tid * 4) = o;
  } else {
    float4 o = {ox, oy, oz, ow};
    *(float4*)((float*)outv + (size_t)row * DMODEL + tid * 4) = o;
  }
}

// =====================================================================
// MFMA flash attention.
// Block = (b, head, 64 queries). 4 waves; wave w owns rows w*16..w*16+15.
// Per key-tile TK (64 or 32):
//   content = (q+rw*S) @ K^T          [MFMA, A in regs]
//   posfull = (q+rr*S) @ Wband^T      [MFMA -> LDS fp32, diag gather]
//   score   = content + posfull[ril] + tok(sel)
//   online softmax fully in C-fragment registers (shfl over lm lanes)
//   O      += P @ V                   [MFMA, P bf16 via LDS, V^T staged]
// LDS row strides are odd multiples of 16B -> conflict-free ds_read_b128.
// pfS/PSm rows are wave-private => only 2 barriers per key-tile.
// =====================================================================
template<int TK>
__global__ __launch_bounds__(256) void attn_mfma(
    const float* __restrict__ q, const unsigned short* __restrict__ k,
    const unsigned short* __restrict__ v, const unsigned short* __restrict__ wrel,
    const float* __restrict__ rw, const float* __restrict__ rr,
    const float* __restrict__ rs, const float* __restrict__ seg,
    const int* __restrict__ ids, unsigned short* __restrict__ vec,
    int Lq, int Lk, int sq, int sk, int sqp, int skp, int rbase, int nrel)
{
  constexpr int NTJ = TK / 16;
  constexpr int KSTR = 72;       // kS row stride (elems): 9*16B rows
  constexpr int VSTR = TK + 8;   // vT/PSm row stride (72 or 40: odd*16B)
  constexpr int BSTR = 72;
  constexpr int PFS = 132;       // posfull fp32 row stride
  __shared__ __align__(16) unsigned short kS[TK * KSTR];
  __shared__ __align__(16) unsigned short vT[64 * VSTR];
  __shared__ __align__(16) unsigned short PSm[64 * VSTR];
  __shared__ __align__(16) unsigned short bandS[128 * BSTR];
  __shared__ float pfS[64 * PFS];
  __shared__ float tb0S[64], tb1S[64];
  __shared__ int idqS[64], idkS[TK];

  const int tid = threadIdx.x;
  const int lane = tid & 63, w = tid >> 6;
  const int lm = lane & 15, lq = lane >> 4;
  const int b = blockIdx.z, n = blockIdx.y;
  const int i0 = blockIdx.x * 64;

  // ---- Q fragments (both bias variants) held in registers ----
  bf16x8 qwf[2], q2f[2];
  {
    const float* qrow = q + ((size_t)b * Lq + i0 + w * 16 + lm) * DMODEL + n * 64;
    const float* rwp = rw + n * 64;
    const float* rrp = rr + n * 64;
#pragma unroll
    for (int ks = 0; ks < 2; ++ks) {
      const int c0 = ks * 32 + lq * 8;
      float qv[8], wv[8], rv[8];
      *(float4*)&qv[0] = *(const float4*)(qrow + c0);
      *(float4*)&qv[4] = *(const float4*)(qrow + c0 + 4);
      *(float4*)&wv[0] = *(const float4*)(rwp + c0);
      *(float4*)&wv[4] = *(const float4*)(rwp + c0 + 4);
      *(float4*)&rv[0] = *(const float4*)(rrp + c0);
      *(float4*)&rv[4] = *(const float4*)(rrp + c0 + 4);
#pragma unroll
      for (int e = 0; e < 8; ++e) {
        qwf[ks][e] = (short)f2bf(qv[e] + wv[e] * QSCALE);
        q2f[ks][e] = (short)f2bf(qv[e] + rv[e] * QSCALE);
      }
    }
  }
  // token-type biases + query ids
  if (tid < 128) {
    const int i = tid >> 1, s_ = tid & 1;
    const float* qr = q + ((size_t)b * Lq + i0 + i) * DMODEL + n * 64;
    const float* sg = seg + (s_ * NHEAD + n) * 64;
    const float* rsp = rs + n * 64;
    float a = 0.f;
    for (int h = 0; h < 64; ++h) a += (qr[h] + rsp[h] * QSCALE) * sg[h];
    if (s_) tb1S[i] = a; else tb0S[i] = a;
  }
  if (tid < 64) idqS[tid] = ids[b * 1024 + sq * (i0 + tid)];

  f32x4 oacc[4];
#pragma unroll
  for (int th = 0; th < 4; ++th) oacc[th] = (f32x4){0.f, 0.f, 0.f, 0.f};
  float mrun[4], lrun[4];
#pragma unroll
  for (int rg = 0; rg < 4; ++rg) { mrun[rg] = -1e30f; lrun[rg] = 0.f; }

  const int W = sqp * 63 + skp * (TK - 1) + 1;  // band rows (<=128)
  const int ibase = w * 16 + lq * 4;

  for (int jt = 0; jt < Lk; jt += TK) {
    __syncthreads();  // previous tile's LDS consumers done
    // ---- stage K (bf16, row-major) ----
    {
      const unsigned short* kb = k + ((size_t)b * Lk + jt) * DMODEL + n * 64;
      for (int e = tid; e < TK * 8; e += 256) {
        const int j = e >> 3, c8 = (e & 7) * 8;
        *(uint4*)&kS[j * KSTR + c8] = *(const uint4*)(kb + (size_t)j * DMODEL + c8);
      }
    }
    // ---- stage V transposed: vT[h][j] ----
    {
      const unsigned short* vb = v + ((size_t)b * Lk + jt) * DMODEL + n * 64;
      if (tid < TK * 4) {
        const int j2 = tid >> 3, h0 = (tid & 7) * 8;
        const uint4 a0 = *(const uint4*)(vb + (size_t)(2 * j2) * DMODEL + h0);
        const uint4 a1 = *(const uint4*)(vb + (size_t)(2 * j2 + 1) * DMODEL + h0);
        const unsigned short* p0 = (const unsigned short*)&a0;
        const unsigned short* p1 = (const unsigned short*)&a1;
#pragma unroll
        for (int e = 0; e < 8; ++e) {
          const int h = h0 + e;
          *(unsigned int*)&vT[h * VSTR + 2 * j2] =
              (unsigned int)p0[e] | ((unsigned int)p1[e] << 16);
        }
      }
    }
    // ---- stage Wrel band (128 rows, clamped to W-1) ----
    const int rlo = sqp * i0 - skp * (jt + TK - 1) + rbase;
    {
      const unsigned short* wb = wrel + ((size_t)n * nrel + rlo) * 64;
      for (int e = tid; e < 128 * 8; e += 256) {
        const int r = e >> 3, c8 = (e & 7) * 8;
        const int rc = r < W ? r : W - 1;
        *(uint4*)&bandS[r * BSTR + c8] = *(const uint4*)(wb + (size_t)rc * 64 + c8);
      }
    }
    if (tid < TK) idkS[tid] = ids[b * 1024 + sk * (jt + tid)];
    __syncthreads();  // staging visible

    // ---- content + positional MFMA ----
    f32x4 cacc[NTJ];
#pragma unroll
    for (int tj = 0; tj < NTJ; ++tj) cacc[tj] = (f32x4){0.f, 0.f, 0.f, 0.f};
    f32x4 pacc[8];
#pragma unroll
    for (int rt = 0; rt < 8; ++rt) pacc[rt] = (f32x4){0.f, 0.f, 0.f, 0.f};
#pragma unroll
    for (int ks = 0; ks < 2; ++ks) {
#pragma unroll
      for (int tj = 0; tj < NTJ; ++tj) {
        const bf16x8 kf =
            *(const bf16x8*)&kS[(tj * 16 + lm) * KSTR + ks * 32 + lq * 8];
        cacc[tj] = __builtin_amdgcn_mfma_f32_16x16x32_bf16(
            qwf[ks], kf, cacc[tj], 0, 0, 0);
      }
#pragma unroll
      for (int rt = 0; rt < 8; ++rt) {
        const bf16x8 bf_ =
            *(const bf16x8*)&bandS[(rt * 16 + lm) * BSTR + ks * 32 + lq * 8];
        pacc[rt] = __builtin_amdgcn_mfma_f32_16x16x32_bf16(
            q2f[ks], bf_, pacc[rt], 0, 0, 0);
      }
    }
    // posfull -> LDS (rows are wave-private; no barrier needed)
#pragma unroll
    for (int rt = 0; rt < 8; ++rt)
#pragma unroll
      for (int rg = 0; rg < 4; ++rg)
        pfS[(ibase + rg) * PFS + rt * 16 + lm] = pacc[rt][rg];

    // ---- gather + token bias -> scores in registers ----
    float sreg[NTJ][4];
#pragma unroll
    for (int tj = 0; tj < NTJ; ++tj) {
      const int jl = tj * 16 + lm;
      const int ik = idkS[jl];
      const int rb_ = skp * (TK - 1 - jl);
#pragma unroll
      for (int rg = 0; rg < 4; ++rg) {
        const int iw = ibase + rg;
        const int ril = sqp * iw + rb_;
        const int iq = idqS[iw];
        const int sel = (iq == ik) | (iq == 2) | (ik == 2);
        sreg[tj][rg] = cacc[tj][rg] + pfS[iw * PFS + ril] +
                       (sel ? tb1S[iw] : tb0S[iw]);
      }
    }
    // ---- online softmax (register-resident; reduce over lm lanes) ----
#pragma unroll
    for (int rg = 0; rg < 4; ++rg) {
      float mx = sreg[0][rg];
#pragma unroll
      for (int tj = 1; tj < NTJ; ++tj) mx = fmaxf(mx, sreg[tj][rg]);
#pragma unroll
      for (int off = 1; off < 16; off <<= 1)
        mx = fmaxf(mx, __shfl_xor(mx, off, 64));
      const float mold = mrun[rg];
      const float mnew = fmaxf(mold, mx);
      float sum = 0.f;
#pragma unroll
      for (int tj = 0; tj < NTJ; ++tj) {
        const float p = __expf(sreg[tj][rg] - mnew);
        const unsigned short pb = f2bf(p);
        PSm[(ibase + rg) * VSTR + tj * 16 + lm] = pb;
        sum += bf2f(pb);
      }
#pragma unroll
      for (int off = 1; off < 16; off <<= 1) sum += __shfl_xor(sum, off, 64);
      const float al = __expf(mold - mnew);
      lrun[rg] = lrun[rg] * al + sum;
      mrun[rg] = mnew;
      oacc[0][rg] *= al; oacc[1][rg] *= al;
      oacc[2][rg] *= al; oacc[3][rg] *= al;
    }
    // ---- P @ V (PSm rows wave-private; in-wave LDS ordering suffices) ----
#pragma unroll
    for (int ks = 0; ks < TK / 32; ++ks) {
      const bf16x8 pa =
          *(const bf16x8*)&PSm[(w * 16 + lm) * VSTR + ks * 32 + lq * 8];
#pragma unroll
      for (int th = 0; th < 4; ++th) {
        const bf16x8 vf =
            *(const bf16x8*)&vT[(th * 16 + lm) * VSTR + ks * 32 + lq * 8];
        oacc[th] = __builtin_amdgcn_mfma_f32_16x16x32_bf16(
            pa, vf, oacc[th], 0, 0, 0);
      }
    }
  }
  // ---- epilogue ----
  unsigned short* ob =
      vec + ((size_t)b * Lq + i0 + ibase) * DMODEL + n * 64 + lm;
#pragma unroll
  for (int rg = 0; rg < 4; ++rg) {
    const float linv = 1.f / lrun[rg];
#pragma unroll
    for (int th = 0; th < 4; ++th)
      ob[(size_t)rg * DMODEL + th * 16] = f2bf(oacc[th][rg] * linv);
  }
}

// =====================================================================
// Host
// =====================================================================
extern "C" void kernel_launch(void* const* d_in, const int* in_sizes, int n_in,
                              void* d_out, int out_size, void* d_ws,
                              size_t ws_size, hipStream_t stream)
{
  const float* final_hidden = (const float*)d_in[0];
  const int* ids = (const int*)d_in[5];
  const float* Wq = (const float*)d_in[6];
  const float* bq = (const float*)d_in[7];
  const float* Wk = (const float*)d_in[8];
  const float* bk = (const float*)d_in[9];
  const float* Wv = (const float*)d_in[10];
  const float* bvv = (const float*)d_in[11];
  const float* rw = (const float*)d_in[12];
  const float* rr = (const float*)d_in[13];
  const float* rs = (const float*)d_in[14];
  const float* rk = (const float*)d_in[15];
  const float* seg = (const float*)d_in[16];
  const float* Wp = (const float*)d_in[17];
  const float* bp = (const float*)d_in[18];
  const float* lng = (const float*)d_in[19];
  const float* lnb = (const float*)d_in[20];

  unsigned char* w8 = (unsigned char*)d_ws;
  const size_t MB = 1024 * 1024;
  unsigned short* hA    = (unsigned short*)(w8 + 0 * MB);   // 4 MB
  unsigned short* hB    = (unsigned short*)(w8 + 4 * MB);   // 4 MB
  unsigned short* upB   = (unsigned short*)(w8 + 8 * MB);   // 4 MB
  float*          qB    = (float*)(w8 + 12 * MB);           // 8 MB fp32
  float*          pB    = (float*)(w8 + 20 * MB);           // 8 MB fp32 (post)
  unsigned short* kBf   = (unsigned short*)(w8 + 28 * MB);  // 4 MB bf16
  unsigned short* vBf   = (unsigned short*)(w8 + 32 * MB);  // 4 MB bf16
  unsigned short* vecB  = (unsigned short*)(w8 + 36 * MB);  // 4 MB bf16
  unsigned short* wrelB = (unsigned short*)(w8 + 40 * MB);  // 4.2 MB bf16 -> 5
  unsigned short* trigB = (unsigned short*)(w8 + 45 * MB);  // 4 MB
  unsigned short* wtq   = (unsigned short*)(w8 + 49 * MB);  // 2 MB each
  unsigned short* wtk   = (unsigned short*)(w8 + 51 * MB);
  unsigned short* wtv   = (unsigned short*)(w8 + 53 * MB);
  unsigned short* wtp   = (unsigned short*)(w8 + 55 * MB);
  unsigned short* rkT   = (unsigned short*)(w8 + 57 * MB);  // ends 59 MB

  // final_hidden -> bf16 into hA
  {
    const int n = BATCH * 256 * DMODEL;
    cvt_k<<<dim3((n + 255) / 256), 256, 0, stream>>>(final_hidden, hA, n);
  }
  const unsigned short* X = hA;

  const dim3 tg(32, 32);
  for (int l = 11; l >= 0; --l) {
    int Lq, Lk, sq, sk, sqp, skp, rmin, rstep, nrel, rbase;
    float sgn;
    if (l <= 3)      { Lq=1024; Lk=1024; sq=1; sk=1; sqp=1; skp=1; rmin=-1023; rstep=1; nrel=2047; rbase=1023; sgn= 1.f; }
    else if (l == 4) { Lq=1024; Lk= 512; sq=1; sk=2; sqp=1; skp=2; rmin=-1022; rstep=1; nrel=2046; rbase=1022; sgn=-1.f; }
    else if (l <= 7) { Lq= 512; Lk= 512; sq=2; sk=2; sqp=1; skp=1; rmin=-1022; rstep=2; nrel=1023; rbase= 511; sgn= 1.f; }
    else if (l == 8) { Lq= 512; Lk= 256; sq=2; sk=4; sqp=1; skp=2; rmin=-1020; rstep=2; nrel=1022; rbase= 510; sgn=-1.f; }
    else             { Lq= 256; Lk= 256; sq=4; sk=4; sqp=1; skp=1; rmin=-1020; rstep=4; nrel= 511; rbase= 255; sgn= 1.f; }

    // block-entry upsample (reference order)
    if (l == 11) {
      const size_t total = (size_t)BATCH * 512 * DMODEL;
      upsample_k<<<dim3((unsigned)((total + 255) / 256)), 256, 0, stream>>>(
          X, upB, 256);
    } else if (l == 7) {
      const size_t total = (size_t)BATCH * 1024 * DMODEL;
      upsample_k<<<dim3((unsigned)((total + 255) / 256)), 256, 0, stream>>>(
          X, upB, 512);
    }
    const bool doUp = (l == 8) || (l == 4);
    const unsigned short* Xq = doUp ? upB : X;
    const int Mq = BATCH * Lq, Mk = BATCH * Lk;
    const int rPad = ((nrel + 127) / 128) * 128;

    // weight transposes (fp32 -> bf16 [n][k])
    tpose_k<<<tg, 256, 0, stream>>>(Wq + (size_t)l * DMODEL * DMODEL, wtq);
    tpose_k<<<tg, 256, 0, stream>>>(Wk + (size_t)l * DMODEL * DMODEL, wtk);
    tpose_k<<<tg, 256, 0, stream>>>(Wv + (size_t)l * DMODEL * DMODEL, wtv);
    tpose_k<<<tg, 256, 0, stream>>>(Wp + (size_t)l * DMODEL * DMODEL, wtp);
    tpose_k<<<tg, 256, 0, stream>>>(rk + (size_t)l * DMODEL * DMODEL, rkT);

    trig_fill<<<dim3((rPad * 512 + 255) / 256), 256, 0, stream>>>(
        trigB, rPad, rmin, rstep, sgn);
    // Wrel[head][r][h] (bf16) = sum_d rkT[head*64+h][d] * trig[r][d]
    gemm_bf16<3><<<dim3(DMODEL / 128, rPad / 128), 256, 0, stream>>>(
        rkT, trigB, nullptr, nullptr, wrelB, DMODEL, nrel, DMODEL, nrel);
    gemm_bf16<1><<<dim3(Mq / 128, 8), 256, 0, stream>>>(
        Xq, wtq, bq + l * DMODEL, nullptr, qB, Mq, DMODEL, DMODEL, 0);
    gemm_bf16<4><<<dim3(Mk / 128, 8), 256, 0, stream>>>(
        X, wtk, bk + l * DMODEL, nullptr, kBf, Mk, DMODEL, DMODEL, 0);
    gemm_bf16<4><<<dim3(Mk / 128, 8), 256, 0, stream>>>(
        X, wtv, bvv + l * DMODEL, nullptr, vBf, Mk, DMODEL, DMODEL, 0);

    dim3 ag(Lq / 64, NHEAD, BATCH);
    if (skp == 1)
      attn_mfma<64><<<ag, 256, 0, stream>>>(qB, kBf, vBf, wrelB,
          rw + l * NHEAD * 64, rr + l * NHEAD * 64, rs + l * NHEAD * 64,
          seg + l * 2 * NHEAD * 64, ids, vecB,
          Lq, Lk, sq, sk, sqp, skp, rbase, nrel);
    else
      attn_mfma<32><<<ag, 256, 0, stream>>>(qB, kBf, vBf, wrelB,
          rw + l * NHEAD * 64, rr + l * NHEAD * 64, rs + l * NHEAD * 64,
          seg + l * 2 * NHEAD * 64, ids, vecB,
          Lq, Lk, sq, sk, sqp, skp, rbase, nrel);

    // post projection + residual
    gemm_bf16<2><<<dim3(Mq / 128, 8), 256, 0, stream>>>(
        vecB, wtp, bp + l * DMODEL, Xq, pB, Mq, DMODEL, DMODEL, 0);
    if (l == 0) {
      ln_k<false><<<dim3(Mq), 256, 0, stream>>>(
          pB, lng + l * DMODEL, lnb + l * DMODEL, d_out);
    } else {
      unsigned short* outBuf = (X == hA) ? hB : hA;
      ln_k<true><<<dim3(Mq), 256, 0, stream>>>(
          pB, lng + l * DMODEL, lnb + l * DMODEL, outBuf);
      X = outBuf;
    }
  }
  (void)in_sizes; (void)n_in; (void)out_size; (void)ws_size;
}

// Round 2
// 2133.815 us; speedup vs baseline: 3.2382x; 1.4467x over previous
//
#include <hip/hip_runtime.h>
#include <math.h>

#define NHEAD 16
#define DMODEL 1024
#define BATCH 2
#define QSCALE 0.125f

typedef __attribute__((ext_vector_type(8))) short bf16x8;
typedef __attribute__((ext_vector_type(4))) float f32x4;

__device__ inline unsigned short f2bf(float x) {
  unsigned int u = __float_as_uint(x);
  u += 0x7FFF + ((u >> 16) & 1);
  return (unsigned short)(u >> 16);
}
__device__ inline float bf2f(unsigned short h) {
  return __uint_as_float(((unsigned int)h) << 16);
}

// async global->LDS, 16B per lane. ldsptr is wave-uniform base; HW writes
// base + lane*16. Global src address is per-lane.
typedef __attribute__((address_space(1))) const unsigned int gu32;
typedef __attribute__((address_space(3))) unsigned int lu32;
__device__ inline void gl_lds16(const unsigned short* g, unsigned short* l) {
  __builtin_amdgcn_global_load_lds((gu32*)g, (lu32*)l, 16, 0, 0);
}

// =====================================================================
// bf16 MFMA GEMM: C[M,N] = A @ B, A bf16 [M][K], Bt bf16 [Npad][K].
// Tile 128x128, BK=64, 256 thr = 4 waves, fragment-contiguous LDS staged
// via global_load_lds (dwordx4).
// MODE 1: (acc+bias)*QSCALE fp32. MODE 2: acc+bias+bf2f(R) fp32.
// MODE 3: wrel bf16 C[head][r][h] scatter.
// =====================================================================
template<int MODE>
__global__ __launch_bounds__(256) void gemm_bf16(
    const unsigned short* __restrict__ A, const unsigned short* __restrict__ Bt,
    const float* __restrict__ bias, const unsigned short* __restrict__ R,
    void* __restrict__ Cv, int M, int N, int K, int nrel)
{
  __shared__ __align__(16) unsigned short smem[32 * 512];
  const int tid = threadIdx.x;
  const int lane = tid & 63, w = tid >> 6;
  const int mw = w >> 1, nw = w & 1;
  const int bm = blockIdx.x * 128, bn = blockIdx.y * 128;
  const int lm = lane & 15, lq = lane >> 4;
  float* Cf = (float*)Cv;
  unsigned short* Cb = (unsigned short*)Cv;

  f32x4 acc[4][4];
#pragma unroll
  for (int i = 0; i < 4; ++i)
#pragma unroll
    for (int j = 0; j < 4; ++j) acc[i][j] = (f32x4){0.f, 0.f, 0.f, 0.f};

  for (int k0 = 0; k0 < K; k0 += 64) {
#pragma unroll
    for (int f = w; f < 16; f += 4) {
      const int kb = f >> 3, mb = f & 7;
      const int gr = bm + mb * 16 + lm;
      const int gc = k0 + kb * 32 + lq * 8;
      gl_lds16(A + (size_t)gr * K + gc, &smem[f * 512]);
      gl_lds16(Bt + (size_t)(bn + mb * 16 + lm) * K + gc, &smem[(16 + f) * 512]);
    }
    __syncthreads();
#pragma unroll
    for (int kb = 0; kb < 2; ++kb) {
      bf16x8 af[4], bf[4];
#pragma unroll
      for (int i = 0; i < 4; ++i)
        af[i] = *(const bf16x8*)(&smem[(kb * 8 + mw * 4 + i) * 512 + lane * 8]);
#pragma unroll
      for (int j = 0; j < 4; ++j)
        bf[j] = *(const bf16x8*)(&smem[(16 + kb * 8 + nw * 4 + j) * 512 + lane * 8]);
#pragma unroll
      for (int i = 0; i < 4; ++i)
#pragma unroll
        for (int j = 0; j < 4; ++j)
          acc[i][j] = __builtin_amdgcn_mfma_f32_16x16x32_bf16(
              af[i], bf[j], acc[i][j], 0, 0, 0);
    }
    __syncthreads();
  }
#pragma unroll
  for (int i = 0; i < 4; ++i) {
#pragma unroll
    for (int j = 0; j < 4; ++j) {
      const int col = bn + nw * 64 + j * 16 + lm;
      if (col >= N) continue;
#pragma unroll
      for (int r = 0; r < 4; ++r) {
        const int row = bm + mw * 64 + i * 16 + lq * 4 + r;
        float vv = acc[i][j][r];
        if (MODE == 1) vv = (vv + bias[col]) * QSCALE;
        else if (MODE == 2) vv = vv + bias[col] + bf2f(R[(size_t)row * N + col]);
        if (MODE == 3)
          Cb[(((size_t)(row >> 6)) * nrel + col) * 64 + (row & 63)] = f2bf(vv);
        else
          Cf[(size_t)row * N + col] = vv;
      }
    }
  }
}

// =====================================================================
// Fused QKV projection: A [M][1024] bf16, Bt = [wtq|wtk|wtv] (3072 rows).
// col in [0,1024): q fp32 *QSCALE; [1024,2048): k bf16; [2048,3072): v bf16.
// colbase lets l4/l8 run k+v only (colbase=1024).
// =====================================================================
__global__ __launch_bounds__(256) void gemm_qkv(
    const unsigned short* __restrict__ A, const unsigned short* __restrict__ Bt,
    const float* __restrict__ bq, const float* __restrict__ bk,
    const float* __restrict__ bv, float* __restrict__ Cq,
    unsigned short* __restrict__ Ck, unsigned short* __restrict__ Cv,
    int M, int K, int colbase)
{
  __shared__ __align__(16) unsigned short smem[32 * 512];
  const int tid = threadIdx.x;
  const int lane = tid & 63, w = tid >> 6;
  const int mw = w >> 1, nw = w & 1;
  const int bm = blockIdx.x * 128, bn = colbase + blockIdx.y * 128;
  const int lm = lane & 15, lq = lane >> 4;

  f32x4 acc[4][4];
#pragma unroll
  for (int i = 0; i < 4; ++i)
#pragma unroll
    for (int j = 0; j < 4; ++j) acc[i][j] = (f32x4){0.f, 0.f, 0.f, 0.f};

  for (int k0 = 0; k0 < K; k0 += 64) {
#pragma unroll
    for (int f = w; f < 16; f += 4) {
      const int kb = f >> 3, mb = f & 7;
      const int gr = bm + mb * 16 + lm;
      const int gc = k0 + kb * 32 + lq * 8;
      gl_lds16(A + (size_t)gr * K + gc, &smem[f * 512]);
      gl_lds16(Bt + (size_t)(bn + mb * 16 + lm) * K + gc, &smem[(16 + f) * 512]);
    }
    __syncthreads();
#pragma unroll
    for (int kb = 0; kb < 2; ++kb) {
      bf16x8 af[4], bf[4];
#pragma unroll
      for (int i = 0; i < 4; ++i)
        af[i] = *(const bf16x8*)(&smem[(kb * 8 + mw * 4 + i) * 512 + lane * 8]);
#pragma unroll
      for (int j = 0; j < 4; ++j)
        bf[j] = *(const bf16x8*)(&smem[(16 + kb * 8 + nw * 4 + j) * 512 + lane * 8]);
#pragma unroll
      for (int i = 0; i < 4; ++i)
#pragma unroll
        for (int j = 0; j < 4; ++j)
          acc[i][j] = __builtin_amdgcn_mfma_f32_16x16x32_bf16(
              af[i], bf[j], acc[i][j], 0, 0, 0);
    }
    __syncthreads();
  }
  const int which = bn >> 10;  // block-uniform
  const float* bias = (which == 0) ? bq : (which == 1) ? bk : bv;
#pragma unroll
  for (int i = 0; i < 4; ++i) {
#pragma unroll
    for (int j = 0; j < 4; ++j) {
      const int col = bn + nw * 64 + j * 16 + lm;
      const int nc = col & 1023;
#pragma unroll
      for (int r = 0; r < 4; ++r) {
        const int row = bm + mw * 64 + i * 16 + lq * 4 + r;
        const float vv = acc[i][j][r] + bias[nc];
        if (which == 0)
          Cq[(size_t)row * 1024 + nc] = vv * QSCALE;
        else if (which == 1)
          Ck[(size_t)row * 1024 + nc] = f2bf(vv);
        else
          Cv[(size_t)row * 1024 + nc] = f2bf(vv);
      }
    }
  }
}

// =====================================================================
// batched transpose + fp32->bf16: 5 matrices [1024][1024] per layer.
// =====================================================================
__global__ __launch_bounds__(256) void tpose5_k(
    const float* __restrict__ s0, const float* __restrict__ s1,
    const float* __restrict__ s2, const float* __restrict__ s3,
    const float* __restrict__ s4, unsigned short* __restrict__ d0,
    unsigned short* __restrict__ d1, unsigned short* __restrict__ d2,
    unsigned short* __restrict__ d3, unsigned short* __restrict__ d4)
{
  const float* in;
  unsigned short* out;
  switch (blockIdx.z) {
    case 0: in = s0; out = d0; break;
    case 1: in = s1; out = d1; break;
    case 2: in = s2; out = d2; break;
    case 3: in = s3; out = d3; break;
    default: in = s4; out = d4; break;
  }
  __shared__ float t[32][33];
  const int bi = blockIdx.x * 32, bj = blockIdx.y * 32;
  const int r = threadIdx.x >> 3, c4 = (threadIdx.x & 7) * 4;
  const float4 v = *(const float4*)(in + (size_t)(bi + r) * 1024 + bj + c4);
  t[r][c4] = v.x; t[r][c4 + 1] = v.y; t[r][c4 + 2] = v.z; t[r][c4 + 3] = v.w;
  __syncthreads();
  ushort4 o;
  o.x = f2bf(t[c4 + 0][r]); o.y = f2bf(t[c4 + 1][r]);
  o.z = f2bf(t[c4 + 2][r]); o.w = f2bf(t[c4 + 3][r]);
  *(ushort4*)(out + (size_t)(bj + r) * 1024 + bi + c4) = o;
}

// fp32 -> bf16 elementwise
__global__ void cvt_k(const float* __restrict__ in,
                      unsigned short* __restrict__ out, int n)
{
  const int i = blockIdx.x * 256 + threadIdx.x;
  if (i < n) out[i] = f2bf(in[i]);
}

// =====================================================================
// trig table (bf16, transposed): T[r][f] = sgn*sin(ang), T[r][f+512]=cos(ang)
// =====================================================================
__global__ void trig_fill(unsigned short* __restrict__ T, int rPad, int rmin,
                          int rstep, float sgn)
{
  const int idx = blockIdx.x * 256 + threadIdx.x;
  if (idx >= rPad * 512) return;
  const int r = idx >> 9, f = idx & 511;
  const float invf = expf((float)f * -(9.210340371976184f / 512.0f));
  const float ang = (float)(rmin + r * rstep) * invf;
  float s, c;
  sincosf(ang, &s, &c);
  T[(size_t)r * 1024 + f] = f2bf(sgn * s);
  T[(size_t)r * 1024 + f + 512] = f2bf(c);
}

// =====================================================================
// upsample (bf16)
// =====================================================================
__global__ void upsample_k(const unsigned short* __restrict__ h,
                           unsigned short* __restrict__ out, int L)
{
  const size_t idx = (size_t)blockIdx.x * 256 + threadIdx.x;
  const size_t total = (size_t)BATCH * 2 * L * DMODEL;
  if (idx >= total) return;
  const int d = (int)(idx & 1023);
  const int t2 = (int)((idx >> 10) % (size_t)(2 * L));
  const int b = (int)((idx >> 10) / (size_t)(2 * L));
  const unsigned short* hb = h + (size_t)b * L * DMODEL;
  float val;
  if ((t2 & 1) == 0) {
    val = bf2f(hb[(size_t)(t2 >> 1) * DMODEL + d]);
  } else {
    const int t = (t2 - 1) >> 1;
    const int prev = (t == 0) ? (L - 1) : (t - 1);
    val = 0.5f * (bf2f(hb[(size_t)t * DMODEL + d]) +
                  bf2f(hb[(size_t)prev * DMODEL + d]));
  }
  out[idx] = f2bf(val);
}

// =====================================================================
// LayerNorm over D=1024
// =====================================================================
template<bool BF16OUT>
__global__ __launch_bounds__(256) void ln_k(
    const float* __restrict__ x, const float* __restrict__ g,
    const float* __restrict__ b, void* __restrict__ outv)
{
  const int row = blockIdx.x;
  const int tid = threadIdx.x;
  const float* xr = x + (size_t)row * DMODEL;
  const float4 xv = *(const float4*)(xr + tid * 4);
  __shared__ float red[4];
  float s = xv.x + xv.y + xv.z + xv.w;
#pragma unroll
  for (int off = 32; off > 0; off >>= 1) s += __shfl_down(s, off, 64);
  if ((tid & 63) == 0) red[tid >> 6] = s;
  __syncthreads();
  const float mean = (red[0] + red[1] + red[2] + red[3]) * (1.f / 1024.f);
  const float dx = xv.x - mean, dy = xv.y - mean;
  const float dz = xv.z - mean, dw = xv.w - mean;
  float vs = dx * dx + dy * dy + dz * dz + dw * dw;
  __syncthreads();
#pragma unroll
  for (int off = 32; off > 0; off >>= 1) vs += __shfl_down(vs, off, 64);
  if ((tid & 63) == 0) red[tid >> 6] = vs;
  __syncthreads();
  const float var = (red[0] + red[1] + red[2] + red[3]) * (1.f / 1024.f);
  const float rstd = rsqrtf(var + 1e-9f);
  const float4 gv = *(const float4*)(g + tid * 4);
  const float4 bv = *(const float4*)(b + tid * 4);
  const float ox = dx * rstd * gv.x + bv.x;
  const float oy = dy * rstd * gv.y + bv.y;
  const float oz = dz * rstd * gv.z + bv.z;
  const float ow = dw * rstd * gv.w + bv.w;
  if (BF16OUT) {
    ushort4 o = {f2bf(ox), f2bf(oy), f2bf(oz), f2bf(ow)};
    *(ushort4*)((unsigned short*)outv + (size_t)row * DMODEL + tid * 4) = o;
  } else {
    float4 o = {ox, oy, oz, ow};
    *(float4*)((float*)outv + (size_t)row * DMODEL + tid * 4) = o;
  }
}

// =====================================================================
// MFMA flash attention. K and Wrel-band staged fragment-contiguous via
// global_load_lds (conflict-free lane*16B reads). V^T reg-staged with
// conflict-light thread map. setprio(1) around MFMA clusters.
// =====================================================================
template<int TK>
__global__ __launch_bounds__(256) void attn_mfma(
    const float* __restrict__ q, const unsigned short* __restrict__ k,
    const unsigned short* __restrict__ v, const unsigned short* __restrict__ wrel,
    const float* __restrict__ rw, const float* __restrict__ rr,
    const float* __restrict__ rs, const float* __restrict__ seg,
    const int* __restrict__ ids, unsigned short* __restrict__ vec,
    int Lq, int Lk, int sq, int sk, int sqp, int skp, int rbase, int nrel)
{
  constexpr int NTJ = TK / 16;
  constexpr int NKF = TK / 8;    // K fragments (512 elems each)
  constexpr int VSTR = TK + 8;   // vT/PSm row stride (odd*16B)
  constexpr int PFS = 132;       // posfull fp32 row stride
  __shared__ __align__(16) unsigned short kF[NKF * 512];
  __shared__ __align__(16) unsigned short bandF[16 * 512];
  __shared__ __align__(16) unsigned short vT[64 * VSTR];
  __shared__ __align__(16) unsigned short PSm[64 * VSTR];
  __shared__ float pfS[64 * PFS];
  __shared__ float tb0S[64], tb1S[64];
  __shared__ int idqS[64], idkS[TK];

  const int tid = threadIdx.x;
  const int lane = tid & 63, w = tid >> 6;
  const int lm = lane & 15, lq = lane >> 4;
  const int b = blockIdx.z, n = blockIdx.y;
  const int i0 = blockIdx.x * 64;

  // ---- Q fragments (both bias variants) held in registers ----
  bf16x8 qwf[2], q2f[2];
  {
    const float* qrow = q + ((size_t)b * Lq + i0 + w * 16 + lm) * DMODEL + n * 64;
    const float* rwp = rw + n * 64;
    const float* rrp = rr + n * 64;
#pragma unroll
    for (int ks = 0; ks < 2; ++ks) {
      const int c0 = ks * 32 + lq * 8;
      float qv[8], wv[8], rv[8];
      *(float4*)&qv[0] = *(const float4*)(qrow + c0);
      *(float4*)&qv[4] = *(const float4*)(qrow + c0 + 4);
      *(float4*)&wv[0] = *(const float4*)(rwp + c0);
      *(float4*)&wv[4] = *(const float4*)(rwp + c0 + 4);
      *(float4*)&rv[0] = *(const float4*)(rrp + c0);
      *(float4*)&rv[4] = *(const float4*)(rrp + c0 + 4);
#pragma unroll
      for (int e = 0; e < 8; ++e) {
        qwf[ks][e] = (short)f2bf(qv[e] + wv[e] * QSCALE);
        q2f[ks][e] = (short)f2bf(qv[e] + rv[e] * QSCALE);
      }
    }
  }
  // token-type biases + query ids
  if (tid < 128) {
    const int i = tid >> 1, s_ = tid & 1;
    const float* qr = q + ((size_t)b * Lq + i0 + i) * DMODEL + n * 64;
    const float* sg = seg + (s_ * NHEAD + n) * 64;
    const float* rsp = rs + n * 64;
    float a = 0.f;
    for (int h = 0; h < 64; ++h) a += (qr[h] + rsp[h] * QSCALE) * sg[h];
    if (s_) tb1S[i] = a; else tb0S[i] = a;
  }
  if (tid < 64) idqS[tid] = ids[b * 1024 + sq * (i0 + tid)];

  f32x4 oacc[4];
#pragma unroll
  for (int th = 0; th < 4; ++th) oacc[th] = (f32x4){0.f, 0.f, 0.f, 0.f};
  float mrun[4], lrun[4];
#pragma unroll
  for (int rg = 0; rg < 4; ++rg) { mrun[rg] = -1e30f; lrun[rg] = 0.f; }

  const int W = sqp * 63 + skp * (TK - 1) + 1;  // band rows (<=128)
  const int ibase = w * 16 + lq * 4;

  for (int jt = 0; jt < Lk; jt += TK) {
    __syncthreads();  // previous tile's LDS consumers done
    // ---- K fragments via global_load_lds ----
    {
      const unsigned short* kb = k + ((size_t)b * Lk + jt) * DMODEL + n * 64;
#pragma unroll
      for (int f = w; f < NKF; f += 4) {
        const int tj = f >> 1, ks = f & 1;
        gl_lds16(kb + (size_t)(tj * 16 + lm) * DMODEL + ks * 32 + lq * 8,
                 &kF[f * 512]);
      }
    }
    // ---- band fragments via global_load_lds (per-lane row clamp) ----
    const int rlo = sqp * i0 - skp * (jt + TK - 1) + rbase;
    {
      const unsigned short* wb = wrel + ((size_t)n * nrel + rlo) * 64;
#pragma unroll
      for (int f = w; f < 16; f += 4) {
        const int rt = f >> 1, ks = f & 1;
        const int r = rt * 16 + lm;
        const int rc = r < W ? r : W - 1;
        gl_lds16(wb + (size_t)rc * 64 + ks * 32 + lq * 8, &bandF[f * 512]);
      }
    }
    // ---- stage V transposed (bank-spread thread map) ----
    {
      const unsigned short* vb = v + ((size_t)b * Lk + jt) * DMODEL + n * 64;
      if (TK == 64) {
        const int j2 = tid & 31, h0 = (tid >> 5) * 8;
        const uint4 a0 = *(const uint4*)(vb + (size_t)(2 * j2) * DMODEL + h0);
        const uint4 a1 = *(const uint4*)(vb + (size_t)(2 * j2 + 1) * DMODEL + h0);
        const unsigned short* p0 = (const unsigned short*)&a0;
        const unsigned short* p1 = (const unsigned short*)&a1;
#pragma unroll
        for (int e = 0; e < 8; ++e)
          *(unsigned int*)&vT[(h0 + e) * VSTR + 2 * j2] =
              (unsigned int)p0[e] | ((unsigned int)p1[e] << 16);
      } else {
        if (tid < 128) {
          const int j2 = tid & 15, h0 = ((tid >> 4) & 7) * 8;
          const uint4 a0 = *(const uint4*)(vb + (size_t)(2 * j2) * DMODEL + h0);
          const uint4 a1 = *(const uint4*)(vb + (size_t)(2 * j2 + 1) * DMODEL + h0);
          const unsigned short* p0 = (const unsigned short*)&a0;
          const unsigned short* p1 = (const unsigned short*)&a1;
#pragma unroll
          for (int e = 0; e < 8; ++e)
            *(unsigned int*)&vT[(h0 + e) * VSTR + 2 * j2] =
                (unsigned int)p0[e] | ((unsigned int)p1[e] << 16);
        }
      }
    }
    if (tid < TK) idkS[tid] = ids[b * 1024 + sk * (jt + tid)];
    __syncthreads();  // staging visible (vmcnt+lgkm drained by barrier)

    // ---- content + positional MFMA ----
    f32x4 cacc[NTJ];
#pragma unroll
    for (int tj = 0; tj < NTJ; ++tj) cacc[tj] = (f32x4){0.f, 0.f, 0.f, 0.f};
    f32x4 pacc[8];
#pragma unroll
    for (int rt = 0; rt < 8; ++rt) pacc[rt] = (f32x4){0.f, 0.f, 0.f, 0.f};
    __builtin_amdgcn_s_setprio(1);
#pragma unroll
    for (int ks = 0; ks < 2; ++ks) {
#pragma unroll
      for (int tj = 0; tj < NTJ; ++tj) {
        const bf16x8 kf = *(const bf16x8*)&kF[(tj * 2 + ks) * 512 + lane * 8];
        cacc[tj] = __builtin_amdgcn_mfma_f32_16x16x32_bf16(
            qwf[ks], kf, cacc[tj], 0, 0, 0);
      }
#pragma unroll
      for (int rt = 0; rt < 8; ++rt) {
        const bf16x8 bf_ = *(const bf16x8*)&bandF[(rt * 2 + ks) * 512 + lane * 8];
        pacc[rt] = __builtin_amdgcn_mfma_f32_16x16x32_bf16(
            q2f[ks], bf_, pacc[rt], 0, 0, 0);
      }
    }
    __builtin_amdgcn_s_setprio(0);
    // posfull -> LDS (rows are wave-private; no barrier needed)
#pragma unroll
    for (int rt = 0; rt < 8; ++rt)
#pragma unroll
      for (int rg = 0; rg < 4; ++rg)
        pfS[(ibase + rg) * PFS + rt * 16 + lm] = pacc[rt][rg];

    // ---- gather + token bias -> scores in registers ----
    float sreg[NTJ][4];
#pragma unroll
    for (int tj = 0; tj < NTJ; ++tj) {
      const int jl = tj * 16 + lm;
      const int ik = idkS[jl];
      const int rb_ = skp * (TK - 1 - jl);
#pragma unroll
      for (int rg = 0; rg < 4; ++rg) {
        const int iw = ibase + rg;
        const int ril = sqp * iw + rb_;
        const int iq = idqS[iw];
        const int sel = (iq == ik) | (iq == 2) | (ik == 2);
        sreg[tj][rg] = cacc[tj][rg] + pfS[iw * PFS + ril] +
                       (sel ? tb1S[iw] : tb0S[iw]);
      }
    }
    // ---- online softmax (register-resident; reduce over lm lanes) ----
#pragma unroll
    for (int rg = 0; rg < 4; ++rg) {
      float mx = sreg[0][rg];
#pragma unroll
      for (int tj = 1; tj < NTJ; ++tj) mx = fmaxf(mx, sreg[tj][rg]);
#pragma unroll
      for (int off = 1; off < 16; off <<= 1)
        mx = fmaxf(mx, __shfl_xor(mx, off, 64));
      const float mold = mrun[rg];
      const float mnew = fmaxf(mold, mx);
      float sum = 0.f;
#pragma unroll
      for (int tj = 0; tj < NTJ; ++tj) {
        const float p = __expf(sreg[tj][rg] - mnew);
        const unsigned short pb = f2bf(p);
        PSm[(ibase + rg) * VSTR + tj * 16 + lm] = pb;
        sum += bf2f(pb);
      }
#pragma unroll
      for (int off = 1; off < 16; off <<= 1) sum += __shfl_xor(sum, off, 64);
      const float al = __expf(mold - mnew);
      lrun[rg] = lrun[rg] * al + sum;
      mrun[rg] = mnew;
      oacc[0][rg] *= al; oacc[1][rg] *= al;
      oacc[2][rg] *= al; oacc[3][rg] *= al;
    }
    // ---- P @ V (PSm rows wave-private; in-wave LDS ordering suffices) ----
    __builtin_amdgcn_s_setprio(1);
#pragma unroll
    for (int ks = 0; ks < TK / 32; ++ks) {
      const bf16x8 pa =
          *(const bf16x8*)&PSm[(w * 16 + lm) * VSTR + ks * 32 + lq * 8];
#pragma unroll
      for (int th = 0; th < 4; ++th) {
        const bf16x8 vf =
            *(const bf16x8*)&vT[(th * 16 + lm) * VSTR + ks * 32 + lq * 8];
        oacc[th] = __builtin_amdgcn_mfma_f32_16x16x32_bf16(
            pa, vf, oacc[th], 0, 0, 0);
      }
    }
    __builtin_amdgcn_s_setprio(0);
  }
  // ---- epilogue ----
  unsigned short* ob =
      vec + ((size_t)b * Lq + i0 + ibase) * DMODEL + n * 64 + lm;
#pragma unroll
  for (int rg = 0; rg < 4; ++rg) {
    const float linv = 1.f / lrun[rg];
#pragma unroll
    for (int th = 0; th < 4; ++th)
      ob[(size_t)rg * DMODEL + th * 16] = f2bf(oacc[th][rg] * linv);
  }
}

// =====================================================================
// Host
// =====================================================================
extern "C" void kernel_launch(void* const* d_in, const int* in_sizes, int n_in,
                              void* d_out, int out_size, void* d_ws,
                              size_t ws_size, hipStream_t stream)
{
  const float* final_hidden = (const float*)d_in[0];
  const int* ids = (const int*)d_in[5];
  const float* Wq = (const float*)d_in[6];
  const float* bq = (const float*)d_in[7];
  const float* Wk = (const float*)d_in[8];
  const float* bk = (const float*)d_in[9];
  const float* Wv = (const float*)d_in[10];
  const float* bvv = (const float*)d_in[11];
  const float* rw = (const float*)d_in[12];
  const float* rr = (const float*)d_in[13];
  const float* rs = (const float*)d_in[14];
  const float* rk = (const float*)d_in[15];
  const float* seg = (const float*)d_in[16];
  const float* Wp = (const float*)d_in[17];
  const float* bp = (const float*)d_in[18];
  const float* lng = (const float*)d_in[19];
  const float* lnb = (const float*)d_in[20];

  unsigned char* w8 = (unsigned char*)d_ws;
  const size_t MB = 1024 * 1024;
  unsigned short* hA    = (unsigned short*)(w8 + 0 * MB);   // 4 MB
  unsigned short* hB    = (unsigned short*)(w8 + 4 * MB);   // 4 MB
  unsigned short* upB   = (unsigned short*)(w8 + 8 * MB);   // 4 MB
  float*          qB    = (float*)(w8 + 12 * MB);           // 8 MB fp32
  float*          pB    = (float*)(w8 + 20 * MB);           // 8 MB fp32
  unsigned short* kBf   = (unsigned short*)(w8 + 28 * MB);  // 4 MB bf16
  unsigned short* vBf   = (unsigned short*)(w8 + 32 * MB);  // 4 MB bf16
  unsigned short* vecB  = (unsigned short*)(w8 + 36 * MB);  // 4 MB bf16
  unsigned short* wrelB = (unsigned short*)(w8 + 40 * MB);  // 4.2 MB -> 5
  unsigned short* wqkv  = (unsigned short*)(w8 + 45 * MB);  // 6 MB (wtq|wtk|wtv)
  unsigned short* wtp   = (unsigned short*)(w8 + 51 * MB);  // 2 MB
  unsigned short* rkT   = (unsigned short*)(w8 + 53 * MB);  // 2 MB
  unsigned short* trigA = (unsigned short*)(w8 + 55 * MB);  // 13.3 MB -> ends 69

  // final_hidden -> bf16 into hA
  {
    const int n = BATCH * 256 * DMODEL;
    cvt_k<<<dim3((n + 255) / 256), 256, 0, stream>>>(final_hidden, hA, n);
  }
  // hoisted trig tables (5 distinct configs)
  trig_fill<<<dim3((2048 * 512 + 255) / 256), 256, 0, stream>>>(
      trigA + (size_t)0 * 1024, 2048, -1023, 1, 1.f);
  trig_fill<<<dim3((2048 * 512 + 255) / 256), 256, 0, stream>>>(
      trigA + (size_t)2048 * 1024, 2048, -1022, 1, -1.f);
  trig_fill<<<dim3((1024 * 512 + 255) / 256), 256, 0, stream>>>(
      trigA + (size_t)4096 * 1024, 1024, -1022, 2, 1.f);
  trig_fill<<<dim3((1024 * 512 + 255) / 256), 256, 0, stream>>>(
      trigA + (size_t)5120 * 1024, 1024, -1020, 2, -1.f);
  trig_fill<<<dim3((512 * 512 + 255) / 256), 256, 0, stream>>>(
      trigA + (size_t)6144 * 1024, 512, -1020, 4, 1.f);

  const unsigned short* X = hA;

  for (int l = 11; l >= 0; --l) {
    int Lq, Lk, sq, sk, sqp, skp, nrel, rbase, troff;
    if (l <= 3)      { Lq=1024; Lk=1024; sq=1; sk=1; sqp=1; skp=1; nrel=2047; rbase=1023; troff=0; }
    else if (l == 4) { Lq=1024; Lk= 512; sq=1; sk=2; sqp=1; skp=2; nrel=2046; rbase=1022; troff=2048; }
    else if (l <= 7) { Lq= 512; Lk= 512; sq=2; sk=2; sqp=1; skp=1; nrel=1023; rbase= 511; troff=4096; }
    else if (l == 8) { Lq= 512; Lk= 256; sq=2; sk=4; sqp=1; skp=2; nrel=1022; rbase= 510; troff=5120; }
    else             { Lq= 256; Lk= 256; sq=4; sk=4; sqp=1; skp=1; nrel= 511; rbase= 255; troff=6144; }

    // block-entry upsample (reference order)
    if (l == 11) {
      const size_t total = (size_t)BATCH * 512 * DMODEL;
      upsample_k<<<dim3((unsigned)((total + 255) / 256)), 256, 0, stream>>>(
          X, upB, 256);
    } else if (l == 7) {
      const size_t total = (size_t)BATCH * 1024 * DMODEL;
      upsample_k<<<dim3((unsigned)((total + 255) / 256)), 256, 0, stream>>>(
          X, upB, 512);
    }
    const bool doUp = (l == 8) || (l == 4);
    const unsigned short* Xq = doUp ? upB : X;
    const int Mq = BATCH * Lq, Mk = BATCH * Lk;
    const int rPad = ((nrel + 127) / 128) * 128;

    // weight transposes (fp32 -> bf16 [n][k]) — one batched launch
    tpose5_k<<<dim3(32, 32, 5), 256, 0, stream>>>(
        Wq + (size_t)l * DMODEL * DMODEL, Wk + (size_t)l * DMODEL * DMODEL,
        Wv + (size_t)l * DMODEL * DMODEL, Wp + (size_t)l * DMODEL * DMODEL,
        rk + (size_t)l * DMODEL * DMODEL,
        wqkv, wqkv + (size_t)DMODEL * DMODEL, wqkv + (size_t)2 * DMODEL * DMODEL,
        wtp, rkT);

    // Wrel[head][r][h] (bf16) = sum_d rkT[head*64+h][d] * trig[r][d]
    gemm_bf16<3><<<dim3(DMODEL / 128, rPad / 128), 256, 0, stream>>>(
        rkT, trigA + (size_t)troff * 1024, nullptr, nullptr, wrelB,
        DMODEL, nrel, DMODEL, nrel);

    if (doUp) {
      gemm_bf16<1><<<dim3(Mq / 128, 8), 256, 0, stream>>>(
          Xq, wqkv, bq + l * DMODEL, nullptr, qB, Mq, DMODEL, DMODEL, 0);
      gemm_qkv<<<dim3(Mk / 128, 16), 256, 0, stream>>>(
          X, wqkv, bq + l * DMODEL, bk + l * DMODEL, bvv + l * DMODEL,
          qB, kBf, vBf, Mk, DMODEL, 1024);
    } else {
      gemm_qkv<<<dim3(Mq / 128, 24), 256, 0, stream>>>(
          X, wqkv, bq + l * DMODEL, bk + l * DMODEL, bvv + l * DMODEL,
          qB, kBf, vBf, Mq, DMODEL, 0);
    }

    dim3 ag(Lq / 64, NHEAD, BATCH);
    if (skp == 1)
      attn_mfma<64><<<ag, 256, 0, stream>>>(qB, kBf, vBf, wrelB,
          rw + l * NHEAD * 64, rr + l * NHEAD * 64, rs + l * NHEAD * 64,
          seg + l * 2 * NHEAD * 64, ids, vecB,
          Lq, Lk, sq, sk, sqp, skp, rbase, nrel);
    else
      attn_mfma<32><<<ag, 256, 0, stream>>>(qB, kBf, vBf, wrelB,
          rw + l * NHEAD * 64, rr + l * NHEAD * 64, rs + l * NHEAD * 64,
          seg + l * 2 * NHEAD * 64, ids, vecB,
          Lq, Lk, sq, sk, sqp, skp, rbase, nrel);

    // post projection + residual
    gemm_bf16<2><<<dim3(Mq / 128, 8), 256, 0, stream>>>(
        vecB, wtp, bp + l * DMODEL, Xq, pB, Mq, DMODEL, DMODEL, 0);
    if (l == 0) {
      ln_k<false><<<dim3(Mq), 256, 0, stream>>>(
          pB, lng + l * DMODEL, lnb + l * DMODEL, d_out);
    } else {
      unsigned short* outBuf = (X == hA) ? hB : hA;
      ln_k<true><<<dim3(Mq), 256, 0, stream>>>(
          pB, lng + l * DMODEL, lnb + l * DMODEL, outBuf);
      X = outBuf;
    }
  }
  (void)in_sizes; (void)n_in; (void)out_size; (void)ws_size;
}

// Round 3
// 2119.324 us; speedup vs baseline: 3.2603x; 1.0068x over previous
//
#include <hip/hip_runtime.h>
#include <math.h>

#define NHEAD 16
#define DMODEL 1024
#define BATCH 2
#define QSCALE 0.125f

typedef __attribute__((ext_vector_type(8))) short bf16x8;
typedef __attribute__((ext_vector_type(4))) float f32x4;

__device__ inline unsigned short f2bf(float x) {
  unsigned int u = __float_as_uint(x);
  u += 0x7FFF + ((u >> 16) & 1);
  return (unsigned short)(u >> 16);
}
__device__ inline float bf2f(unsigned short h) {
  return __uint_as_float(((unsigned int)h) << 16);
}

// async global->LDS, 16B per lane. ldsptr is wave-uniform base; HW writes
// base + lane*16. Global src address is per-lane.
typedef __attribute__((address_space(1))) const unsigned int gu32;
typedef __attribute__((address_space(3))) unsigned int lu32;
__device__ inline void gl_lds16(const unsigned short* g, unsigned short* l) {
  __builtin_amdgcn_global_load_lds((gu32*)g, (lu32*)l, 16, 0, 0);
}

// =====================================================================
// bf16 MFMA GEMM: C[M,N] = A @ B, A bf16 [M][K], Bt bf16 [Npad][K].
// Tile 128x128, BK=64, 256 thr = 4 waves, fragment-contiguous LDS staged
// via global_load_lds (dwordx4).
// MODE 1: (acc+bias)*QSCALE fp32. MODE 2: acc+bias+bf2f(R) fp32.
// MODE 3: wrel bf16 C[head][r][h] scatter.
// =====================================================================
template<int MODE>
__global__ __launch_bounds__(256) void gemm_bf16(
    const unsigned short* __restrict__ A, const unsigned short* __restrict__ Bt,
    const float* __restrict__ bias, const unsigned short* __restrict__ R,
    void* __restrict__ Cv, int M, int N, int K, int nrel)
{
  __shared__ __align__(16) unsigned short smem[32 * 512];
  const int tid = threadIdx.x;
  const int lane = tid & 63, w = tid >> 6;
  const int mw = w >> 1, nw = w & 1;
  const int bm = blockIdx.x * 128, bn = blockIdx.y * 128;
  const int lm = lane & 15, lq = lane >> 4;
  float* Cf = (float*)Cv;
  unsigned short* Cb = (unsigned short*)Cv;

  f32x4 acc[4][4];
#pragma unroll
  for (int i = 0; i < 4; ++i)
#pragma unroll
    for (int j = 0; j < 4; ++j) acc[i][j] = (f32x4){0.f, 0.f, 0.f, 0.f};

  for (int k0 = 0; k0 < K; k0 += 64) {
#pragma unroll
    for (int f = w; f < 16; f += 4) {
      const int kb = f >> 3, mb = f & 7;
      const int gr = bm + mb * 16 + lm;
      const int gc = k0 + kb * 32 + lq * 8;
      gl_lds16(A + (size_t)gr * K + gc, &smem[f * 512]);
      gl_lds16(Bt + (size_t)(bn + mb * 16 + lm) * K + gc, &smem[(16 + f) * 512]);
    }
    __syncthreads();
#pragma unroll
    for (int kb = 0; kb < 2; ++kb) {
      bf16x8 af[4], bf[4];
#pragma unroll
      for (int i = 0; i < 4; ++i)
        af[i] = *(const bf16x8*)(&smem[(kb * 8 + mw * 4 + i) * 512 + lane * 8]);
#pragma unroll
      for (int j = 0; j < 4; ++j)
        bf[j] = *(const bf16x8*)(&smem[(16 + kb * 8 + nw * 4 + j) * 512 + lane * 8]);
#pragma unroll
      for (int i = 0; i < 4; ++i)
#pragma unroll
        for (int j = 0; j < 4; ++j)
          acc[i][j] = __builtin_amdgcn_mfma_f32_16x16x32_bf16(
              af[i], bf[j], acc[i][j], 0, 0, 0);
    }
    __syncthreads();
  }
#pragma unroll
  for (int i = 0; i < 4; ++i) {
#pragma unroll
    for (int j = 0; j < 4; ++j) {
      const int col = bn + nw * 64 + j * 16 + lm;
      if (col >= N) continue;
#pragma unroll
      for (int r = 0; r < 4; ++r) {
        const int row = bm + mw * 64 + i * 16 + lq * 4 + r;
        float vv = acc[i][j][r];
        if (MODE == 1) vv = (vv + bias[col]) * QSCALE;
        else if (MODE == 2) vv = vv + bias[col] + bf2f(R[(size_t)row * N + col]);
        if (MODE == 3)
          Cb[(((size_t)(row >> 6)) * nrel + col) * 64 + (row & 63)] = f2bf(vv);
        else
          Cf[(size_t)row * N + col] = vv;
      }
    }
  }
}

// =====================================================================
// Fused QKV projection: A [M][1024] bf16, Bt = [wtq|wtk|wtv] (3072 rows).
// col in [0,1024): q fp32 *QSCALE; [1024,2048): k bf16; [2048,3072): v bf16.
// colbase lets l4/l8 run k+v only (colbase=1024).
// =====================================================================
__global__ __launch_bounds__(256) void gemm_qkv(
    const unsigned short* __restrict__ A, const unsigned short* __restrict__ Bt,
    const float* __restrict__ bq, const float* __restrict__ bk,
    const float* __restrict__ bv, float* __restrict__ Cq,
    unsigned short* __restrict__ Ck, unsigned short* __restrict__ Cv,
    int M, int K, int colbase)
{
  __shared__ __align__(16) unsigned short smem[32 * 512];
  const int tid = threadIdx.x;
  const int lane = tid & 63, w = tid >> 6;
  const int mw = w >> 1, nw = w & 1;
  const int bm = blockIdx.x * 128, bn = colbase + blockIdx.y * 128;
  const int lm = lane & 15, lq = lane >> 4;

  f32x4 acc[4][4];
#pragma unroll
  for (int i = 0; i < 4; ++i)
#pragma unroll
    for (int j = 0; j < 4; ++j) acc[i][j] = (f32x4){0.f, 0.f, 0.f, 0.f};

  for (int k0 = 0; k0 < K; k0 += 64) {
#pragma unroll
    for (int f = w; f < 16; f += 4) {
      const int kb = f >> 3, mb = f & 7;
      const int gr = bm + mb * 16 + lm;
      const int gc = k0 + kb * 32 + lq * 8;
      gl_lds16(A + (size_t)gr * K + gc, &smem[f * 512]);
      gl_lds16(Bt + (size_t)(bn + mb * 16 + lm) * K + gc, &smem[(16 + f) * 512]);
    }
    __syncthreads();
#pragma unroll
    for (int kb = 0; kb < 2; ++kb) {
      bf16x8 af[4], bf[4];
#pragma unroll
      for (int i = 0; i < 4; ++i)
        af[i] = *(const bf16x8*)(&smem[(kb * 8 + mw * 4 + i) * 512 + lane * 8]);
#pragma unroll
      for (int j = 0; j < 4; ++j)
        bf[j] = *(const bf16x8*)(&smem[(16 + kb * 8 + nw * 4 + j) * 512 + lane * 8]);
#pragma unroll
      for (int i = 0; i < 4; ++i)
#pragma unroll
        for (int j = 0; j < 4; ++j)
          acc[i][j] = __builtin_amdgcn_mfma_f32_16x16x32_bf16(
              af[i], bf[j], acc[i][j], 0, 0, 0);
    }
    __syncthreads();
  }
  const int which = bn >> 10;  // block-uniform
  const float* bias = (which == 0) ? bq : (which == 1) ? bk : bv;
#pragma unroll
  for (int i = 0; i < 4; ++i) {
#pragma unroll
    for (int j = 0; j < 4; ++j) {
      const int col = bn + nw * 64 + j * 16 + lm;
      const int nc = col & 1023;
#pragma unroll
      for (int r = 0; r < 4; ++r) {
        const int row = bm + mw * 64 + i * 16 + lq * 4 + r;
        const float vv = acc[i][j][r] + bias[nc];
        if (which == 0)
          Cq[(size_t)row * 1024 + nc] = vv * QSCALE;
        else if (which == 1)
          Ck[(size_t)row * 1024 + nc] = f2bf(vv);
        else
          Cv[(size_t)row * 1024 + nc] = f2bf(vv);
      }
    }
  }
}

// =====================================================================
// batched transpose + fp32->bf16: 5 matrices [1024][1024] per layer.
// =====================================================================
__global__ __launch_bounds__(256) void tpose5_k(
    const float* __restrict__ s0, const float* __restrict__ s1,
    const float* __restrict__ s2, const float* __restrict__ s3,
    const float* __restrict__ s4, unsigned short* __restrict__ d0,
    unsigned short* __restrict__ d1, unsigned short* __restrict__ d2,
    unsigned short* __restrict__ d3, unsigned short* __restrict__ d4)
{
  const float* in;
  unsigned short* out;
  switch (blockIdx.z) {
    case 0: in = s0; out = d0; break;
    case 1: in = s1; out = d1; break;
    case 2: in = s2; out = d2; break;
    case 3: in = s3; out = d3; break;
    default: in = s4; out = d4; break;
  }
  __shared__ float t[32][33];
  const int bi = blockIdx.x * 32, bj = blockIdx.y * 32;
  const int r = threadIdx.x >> 3, c4 = (threadIdx.x & 7) * 4;
  const float4 v = *(const float4*)(in + (size_t)(bi + r) * 1024 + bj + c4);
  t[r][c4] = v.x; t[r][c4 + 1] = v.y; t[r][c4 + 2] = v.z; t[r][c4 + 3] = v.w;
  __syncthreads();
  ushort4 o;
  o.x = f2bf(t[c4 + 0][r]); o.y = f2bf(t[c4 + 1][r]);
  o.z = f2bf(t[c4 + 2][r]); o.w = f2bf(t[c4 + 3][r]);
  *(ushort4*)(out + (size_t)(bj + r) * 1024 + bi + c4) = o;
}

// fp32 -> bf16 elementwise
__global__ void cvt_k(const float* __restrict__ in,
                      unsigned short* __restrict__ out, int n)
{
  const int i = blockIdx.x * 256 + threadIdx.x;
  if (i < n) out[i] = f2bf(in[i]);
}

// =====================================================================
// trig table (bf16, transposed): T[r][f] = sgn*sin(ang), T[r][f+512]=cos(ang)
// =====================================================================
__global__ void trig_fill(unsigned short* __restrict__ T, int rPad, int rmin,
                          int rstep, float sgn)
{
  const int idx = blockIdx.x * 256 + threadIdx.x;
  if (idx >= rPad * 512) return;
  const int r = idx >> 9, f = idx & 511;
  const float invf = expf((float)f * -(9.210340371976184f / 512.0f));
  const float ang = (float)(rmin + r * rstep) * invf;
  float s, c;
  sincosf(ang, &s, &c);
  T[(size_t)r * 1024 + f] = f2bf(sgn * s);
  T[(size_t)r * 1024 + f + 512] = f2bf(c);
}

// =====================================================================
// upsample (bf16)
// =====================================================================
__global__ void upsample_k(const unsigned short* __restrict__ h,
                           unsigned short* __restrict__ out, int L)
{
  const size_t idx = (size_t)blockIdx.x * 256 + threadIdx.x;
  const size_t total = (size_t)BATCH * 2 * L * DMODEL;
  if (idx >= total) return;
  const int d = (int)(idx & 1023);
  const int t2 = (int)((idx >> 10) % (size_t)(2 * L));
  const int b = (int)((idx >> 10) / (size_t)(2 * L));
  const unsigned short* hb = h + (size_t)b * L * DMODEL;
  float val;
  if ((t2 & 1) == 0) {
    val = bf2f(hb[(size_t)(t2 >> 1) * DMODEL + d]);
  } else {
    const int t = (t2 - 1) >> 1;
    const int prev = (t == 0) ? (L - 1) : (t - 1);
    val = 0.5f * (bf2f(hb[(size_t)t * DMODEL + d]) +
                  bf2f(hb[(size_t)prev * DMODEL + d]));
  }
  out[idx] = f2bf(val);
}

// =====================================================================
// LayerNorm over D=1024
// =====================================================================
template<bool BF16OUT>
__global__ __launch_bounds__(256) void ln_k(
    const float* __restrict__ x, const float* __restrict__ g,
    const float* __restrict__ b, void* __restrict__ outv)
{
  const int row = blockIdx.x;
  const int tid = threadIdx.x;
  const float* xr = x + (size_t)row * DMODEL;
  const float4 xv = *(const float4*)(xr + tid * 4);
  __shared__ float red[4];
  float s = xv.x + xv.y + xv.z + xv.w;
#pragma unroll
  for (int off = 32; off > 0; off >>= 1) s += __shfl_down(s, off, 64);
  if ((tid & 63) == 0) red[tid >> 6] = s;
  __syncthreads();
  const float mean = (red[0] + red[1] + red[2] + red[3]) * (1.f / 1024.f);
  const float dx = xv.x - mean, dy = xv.y - mean;
  const float dz = xv.z - mean, dw = xv.w - mean;
  float vs = dx * dx + dy * dy + dz * dz + dw * dw;
  __syncthreads();
#pragma unroll
  for (int off = 32; off > 0; off >>= 1) vs += __shfl_down(vs, off, 64);
  if ((tid & 63) == 0) red[tid >> 6] = vs;
  __syncthreads();
  const float var = (red[0] + red[1] + red[2] + red[3]) * (1.f / 1024.f);
  const float rstd = rsqrtf(var + 1e-9f);
  const float4 gv = *(const float4*)(g + tid * 4);
  const float4 bv = *(const float4*)(b + tid * 4);
  const float ox = dx * rstd * gv.x + bv.x;
  const float oy = dy * rstd * gv.y + bv.y;
  const float oz = dz * rstd * gv.z + bv.z;
  const float ow = dw * rstd * gv.w + bv.w;
  if (BF16OUT) {
    ushort4 o = {f2bf(ox), f2bf(oy), f2bf(oz), f2bf(ow)};
    *(ushort4*)((unsigned short*)outv + (size_t)row * DMODEL + tid * 4) = o;
  } else {
    float4 o = {ox, oy, oz, ow};
    *(float4*)((float*)outv + (size_t)row * DMODEL + tid * 4) = o;
  }
}

// =====================================================================
// MFMA flash attention, double-buffered + counted-prefetch (T3/T4 style).
// Per tile t:
//   __syncthreads (A): drains tile t's prefetch (vmcnt 0), syncs epilogue
//   commit idk+vT(t) from regs; ISSUE prefetch t+1 (gl_lds K/band, V->regs)
//   lgkmcnt(0); s_barrier (B)  [prefetch stays in flight]
//   QK + per-wave band-window MFMA (reads S[t&1])
//   lgkmcnt(0); s_barrier (C)  [all waves done reading S[t&1]]
//   pfW (aliases S[t&1] per-wave) -> gather -> softmax -> PSw -> PV
// Per-wave band window: wave w needs band rows [w*16, w*16+79) only
// (sqp==1 in all configs) -> 5 band tiles instead of 8.
// =====================================================================
template<int TK>
__global__ __launch_bounds__(256) void attn_mfma(
    const float* __restrict__ q, const unsigned short* __restrict__ k,
    const unsigned short* __restrict__ v, const unsigned short* __restrict__ wrel,
    const float* __restrict__ rw, const float* __restrict__ rr,
    const float* __restrict__ rs, const float* __restrict__ seg,
    const int* __restrict__ ids, unsigned short* __restrict__ vec,
    int Lq, int Lk, int sq, int sk, int sqp, int skp, int rbase, int nrel)
{
  constexpr int NTJ = TK / 16;
  constexpr int NKF = TK / 8;                 // K fragments (512 elems each)
  constexpr int VSTR = TK + 8;                // vT/PSw row stride (odd*16B)
  constexpr int SB_STAGE = (NKF + 16) * 1024; // kF + bandF bytes
  constexpr int WREG = 5504;                  // per-wave pfW/PSw region bytes
  constexpr int SB = (SB_STAGE > 4 * WREG) ? SB_STAGE : 4 * WREG;
  __shared__ __align__(16) unsigned char Sb[2][SB];
  __shared__ __align__(16) unsigned short vT[2][64 * VSTR];
  __shared__ float tb0S[64], tb1S[64];
  __shared__ int idqS[64], idkS[TK];

  const int tid = threadIdx.x;
  const int lane = tid & 63, w = tid >> 6;
  const int lm = lane & 15, lq = lane >> 4;
  const int b = blockIdx.z, n = blockIdx.y;
  const int i0 = blockIdx.x * 64;
  const int W = 64 + skp * (TK - 1);          // band rows (sqp==1)
  const int ibase = w * 16 + lq * 4;
  const int nt = Lk / TK;

  // ---- Q fragments (both bias variants) held in registers ----
  bf16x8 qwf[2], q2f[2];
  {
    const float* qrow = q + ((size_t)b * Lq + i0 + w * 16 + lm) * DMODEL + n * 64;
    const float* rwp = rw + n * 64;
    const float* rrp = rr + n * 64;
#pragma unroll
    for (int ks = 0; ks < 2; ++ks) {
      const int c0 = ks * 32 + lq * 8;
      float qv[8], wv[8], rv[8];
      *(float4*)&qv[0] = *(const float4*)(qrow + c0);
      *(float4*)&qv[4] = *(const float4*)(qrow + c0 + 4);
      *(float4*)&wv[0] = *(const float4*)(rwp + c0);
      *(float4*)&wv[4] = *(const float4*)(rwp + c0 + 4);
      *(float4*)&rv[0] = *(const float4*)(rrp + c0);
      *(float4*)&rv[4] = *(const float4*)(rrp + c0 + 4);
#pragma unroll
      for (int e = 0; e < 8; ++e) {
        qwf[ks][e] = (short)f2bf(qv[e] + wv[e] * QSCALE);
        q2f[ks][e] = (short)f2bf(qv[e] + rv[e] * QSCALE);
      }
    }
  }
  // token-type biases + query ids
  if (tid < 128) {
    const int i = tid >> 1, s_ = tid & 1;
    const float* qr = q + ((size_t)b * Lq + i0 + i) * DMODEL + n * 64;
    const float* sg = seg + (s_ * NHEAD + n) * 64;
    const float* rsp = rs + n * 64;
    float a = 0.f;
    for (int h = 0; h < 64; ++h) a += (qr[h] + rsp[h] * QSCALE) * sg[h];
    if (s_) tb1S[i] = a; else tb0S[i] = a;
  }
  if (tid < 64) idqS[tid] = ids[b * 1024 + sq * (i0 + tid)];

  // V-transpose thread map (bank-spread)
  int vj2, vh0;
  if (TK == 64) { vj2 = tid & 31; vh0 = (tid >> 5) * 8; }
  else          { vj2 = tid & 15; vh0 = ((tid >> 4) & 7) * 8; }
  const bool vact = (TK == 64) || (tid < 128);

  f32x4 oacc[4];
#pragma unroll
  for (int th = 0; th < 4; ++th) oacc[th] = (f32x4){0.f, 0.f, 0.f, 0.f};
  float mrun[4], lrun[4];
#pragma unroll
  for (int rg = 0; rg < 4; ++rg) { mrun[rg] = -1e30f; lrun[rg] = 0.f; }

  // ---- staging helpers ----
  auto STAGE = [&](int jt, int bufi) {
    unsigned short* kF = (unsigned short*)&Sb[bufi][0];
    unsigned short* bF = (unsigned short*)&Sb[bufi][NKF * 1024];
    const unsigned short* kb = k + ((size_t)b * Lk + jt) * DMODEL + n * 64;
#pragma unroll
    for (int f = w; f < NKF; f += 4) {
      const int tj = f >> 1, ks = f & 1;
      gl_lds16(kb + (size_t)(tj * 16 + lm) * DMODEL + ks * 32 + lq * 8,
               &kF[f * 512]);
    }
    const int rlo = i0 - skp * (jt + TK - 1) + rbase;
    const unsigned short* wb = wrel + ((size_t)n * nrel + rlo) * 64;
#pragma unroll
    for (int f = w; f < 16; f += 4) {
      const int rt = f >> 1, ks = f & 1;
      const int r = rt * 16 + lm;
      const int rc = r < W ? r : W - 1;
      gl_lds16(wb + (size_t)rc * 64 + ks * 32 + lq * 8, &bF[f * 512]);
    }
  };
  uint4 vA0, vA1, vB0, vB1;
  auto VLOAD = [&](int jt, uint4& a0, uint4& a1) {
    if (vact) {
      const unsigned short* vb = v + ((size_t)b * Lk + jt) * DMODEL + n * 64;
      a0 = *(const uint4*)(vb + (size_t)(2 * vj2) * DMODEL + vh0);
      a1 = *(const uint4*)(vb + (size_t)(2 * vj2 + 1) * DMODEL + vh0);
    }
  };
  auto VSTORE = [&](int bufi, const uint4& a0, const uint4& a1) {
    if (vact) {
      const unsigned short* p0 = (const unsigned short*)&a0;
      const unsigned short* p1 = (const unsigned short*)&a1;
      unsigned short* vt = &vT[bufi][0];
#pragma unroll
      for (int e = 0; e < 8; ++e)
        *(unsigned int*)&vt[(vh0 + e) * VSTR + 2 * vj2] =
            (unsigned int)p0[e] | ((unsigned int)p1[e] << 16);
    }
  };
  int ridk = 0;

  // ---- prologue: prefetch tile 0 ----
  STAGE(0, 0);
  VLOAD(0, vA0, vA1);
  if (tid < TK) ridk = ids[b * 1024 + sk * tid];

  for (int t = 0; t < nt; ++t) {
    const int jt = t * TK;
    const int buf = t & 1;
    __syncthreads();  // A: vmcnt(0)+lgkmcnt(0)+barrier — tile t data landed
    __builtin_amdgcn_sched_barrier(0);
    // commit tile-t regs to LDS; issue prefetch t+1 (stays in flight)
    if (tid < TK) idkS[tid] = ridk;
    if (buf == 0) {
      VSTORE(0, vA0, vA1);
      if (t + 1 < nt) VLOAD(jt + TK, vB0, vB1);
    } else {
      VSTORE(1, vB0, vB1);
      if (t + 1 < nt) VLOAD(jt + TK, vA0, vA1);
    }
    if (t + 1 < nt) {
      STAGE(jt + TK, buf ^ 1);
      if (tid < TK) ridk = ids[b * 1024 + sk * (jt + TK + tid)];
    }
    asm volatile("s_waitcnt lgkmcnt(0)" ::: "memory");
    __builtin_amdgcn_s_barrier();  // B: vT/idk visible; prefetch in flight
    __builtin_amdgcn_sched_barrier(0);

    // ---- content + per-wave-window positional MFMA ----
    const unsigned short* kF = (const unsigned short*)&Sb[buf][0];
    const unsigned short* bF = (const unsigned short*)&Sb[buf][NKF * 1024];
    f32x4 cacc[NTJ];
#pragma unroll
    for (int tj = 0; tj < NTJ; ++tj) cacc[tj] = (f32x4){0.f, 0.f, 0.f, 0.f};
    f32x4 pacc[5];
#pragma unroll
    for (int rt = 0; rt < 5; ++rt) pacc[rt] = (f32x4){0.f, 0.f, 0.f, 0.f};
    __builtin_amdgcn_s_setprio(1);
#pragma unroll
    for (int ks = 0; ks < 2; ++ks) {
#pragma unroll
      for (int tj = 0; tj < NTJ; ++tj) {
        const bf16x8 kf = *(const bf16x8*)&kF[(tj * 2 + ks) * 512 + lane * 8];
        cacc[tj] = __builtin_amdgcn_mfma_f32_16x16x32_bf16(
            qwf[ks], kf, cacc[tj], 0, 0, 0);
      }
#pragma unroll
      for (int rt = 0; rt < 5; ++rt) {
        const bf16x8 bfr =
            *(const bf16x8*)&bF[((w + rt) * 2 + ks) * 512 + lane * 8];
        pacc[rt] = __builtin_amdgcn_mfma_f32_16x16x32_bf16(
            q2f[ks], bfr, pacc[rt], 0, 0, 0);
      }
    }
    __builtin_amdgcn_s_setprio(0);
    asm volatile("s_waitcnt lgkmcnt(0)" ::: "memory");
    __builtin_amdgcn_s_barrier();  // C: all waves done reading Sb[buf]
    __builtin_amdgcn_sched_barrier(0);

    // ---- pfW window (aliases Sb[buf], per-wave region) ----
    float* pfW = (float*)&Sb[buf][w * WREG];  // [16][85]
#pragma unroll
    for (int rt = 0; rt < 5; ++rt)
#pragma unroll
      for (int rg = 0; rg < 4; ++rg)
        pfW[(lq * 4 + rg) * 85 + rt * 16 + lm] = pacc[rt][rg];

    // ---- gather + token bias -> scores in registers ----
    float sreg[NTJ][4];
#pragma unroll
    for (int tj = 0; tj < NTJ; ++tj) {
      const int jl = tj * 16 + lm;
      const int ik = idkS[jl];
      const int roff = skp * (TK - 1 - jl);
#pragma unroll
      for (int rg = 0; rg < 4; ++rg) {
        const int iw = ibase + rg;
        const int iq = idqS[iw];
        const int sel = (iq == ik) | (iq == 2) | (ik == 2);
        sreg[tj][rg] = cacc[tj][rg] + pfW[(lq * 4 + rg) * 85 + lq * 4 + rg + roff] +
                       (sel ? tb1S[iw] : tb0S[iw]);
      }
    }
    // ---- online softmax (register-resident; reduce over lm lanes) ----
    unsigned short* PSw = (unsigned short*)&Sb[buf][w * WREG];  // [16][VSTR]
#pragma unroll
    for (int rg = 0; rg < 4; ++rg) {
      float mx = sreg[0][rg];
#pragma unroll
      for (int tj = 1; tj < NTJ; ++tj) mx = fmaxf(mx, sreg[tj][rg]);
#pragma unroll
      for (int off = 1; off < 16; off <<= 1)
        mx = fmaxf(mx, __shfl_xor(mx, off, 64));
      const float mold = mrun[rg];
      const float mnew = fmaxf(mold, mx);
      float sum = 0.f;
#pragma unroll
      for (int tj = 0; tj < NTJ; ++tj) {
        const float p = __expf(sreg[tj][rg] - mnew);
        const unsigned short pb = f2bf(p);
        PSw[(lq * 4 + rg) * VSTR + tj * 16 + lm] = pb;
        sum += bf2f(pb);
      }
#pragma unroll
      for (int off = 1; off < 16; off <<= 1) sum += __shfl_xor(sum, off, 64);
      const float al = __expf(mold - mnew);
      lrun[rg] = lrun[rg] * al + sum;
      mrun[rg] = mnew;
      oacc[0][rg] *= al; oacc[1][rg] *= al;
      oacc[2][rg] *= al; oacc[3][rg] *= al;
    }
    // ---- P @ V (PSw/vT reads are wave-local / tile-stable) ----
    __builtin_amdgcn_s_setprio(1);
#pragma unroll
    for (int ks = 0; ks < TK / 32; ++ks) {
      const bf16x8 pa = *(const bf16x8*)&PSw[lm * VSTR + ks * 32 + lq * 8];
#pragma unroll
      for (int th = 0; th < 4; ++th) {
        const bf16x8 vf =
            *(const bf16x8*)&vT[buf][(th * 16 + lm) * VSTR + ks * 32 + lq * 8];
        oacc[th] = __builtin_amdgcn_mfma_f32_16x16x32_bf16(
            pa, vf, oacc[th], 0, 0, 0);
      }
    }
    __builtin_amdgcn_s_setprio(0);
  }
  // ---- epilogue ----
  unsigned short* ob =
      vec + ((size_t)b * Lq + i0 + ibase) * DMODEL + n * 64 + lm;
#pragma unroll
  for (int rg = 0; rg < 4; ++rg) {
    const float linv = 1.f / lrun[rg];
#pragma unroll
    for (int th = 0; th < 4; ++th)
      ob[(size_t)rg * DMODEL + th * 16] = f2bf(oacc[th][rg] * linv);
  }
}

// =====================================================================
// Host
// =====================================================================
extern "C" void kernel_launch(void* const* d_in, const int* in_sizes, int n_in,
                              void* d_out, int out_size, void* d_ws,
                              size_t ws_size, hipStream_t stream)
{
  const float* final_hidden = (const float*)d_in[0];
  const int* ids = (const int*)d_in[5];
  const float* Wq = (const float*)d_in[6];
  const float* bq = (const float*)d_in[7];
  const float* Wk = (const float*)d_in[8];
  const float* bk = (const float*)d_in[9];
  const float* Wv = (const float*)d_in[10];
  const float* bvv = (const float*)d_in[11];
  const float* rw = (const float*)d_in[12];
  const float* rr = (const float*)d_in[13];
  const float* rs = (const float*)d_in[14];
  const float* rk = (const float*)d_in[15];
  const float* seg = (const float*)d_in[16];
  const float* Wp = (const float*)d_in[17];
  const float* bp = (const float*)d_in[18];
  const float* lng = (const float*)d_in[19];
  const float* lnb = (const float*)d_in[20];

  unsigned char* w8 = (unsigned char*)d_ws;
  const size_t MB = 1024 * 1024;
  unsigned short* hA    = (unsigned short*)(w8 + 0 * MB);   // 4 MB
  unsigned short* hB    = (unsigned short*)(w8 + 4 * MB);   // 4 MB
  unsigned short* upB   = (unsigned short*)(w8 + 8 * MB);   // 4 MB
  float*          qB    = (float*)(w8 + 12 * MB);           // 8 MB fp32
  float*          pB    = (float*)(w8 + 20 * MB);           // 8 MB fp32
  unsigned short* kBf   = (unsigned short*)(w8 + 28 * MB);  // 4 MB bf16
  unsigned short* vBf   = (unsigned short*)(w8 + 32 * MB);  // 4 MB bf16
  unsigned short* vecB  = (unsigned short*)(w8 + 36 * MB);  // 4 MB bf16
  unsigned short* wrelB = (unsigned short*)(w8 + 40 * MB);  // 4.2 MB -> 5
  unsigned short* wqkv  = (unsigned short*)(w8 + 45 * MB);  // 6 MB (wtq|wtk|wtv)
  unsigned short* wtp   = (unsigned short*)(w8 + 51 * MB);  // 2 MB
  unsigned short* rkT   = (unsigned short*)(w8 + 53 * MB);  // 2 MB
  unsigned short* trigA = (unsigned short*)(w8 + 55 * MB);  // 13.3 MB -> ends 69

  // final_hidden -> bf16 into hA
  {
    const int n = BATCH * 256 * DMODEL;
    cvt_k<<<dim3((n + 255) / 256), 256, 0, stream>>>(final_hidden, hA, n);
  }
  // hoisted trig tables (5 distinct configs)
  trig_fill<<<dim3((2048 * 512 + 255) / 256), 256, 0, stream>>>(
      trigA + (size_t)0 * 1024, 2048, -1023, 1, 1.f);
  trig_fill<<<dim3((2048 * 512 + 255) / 256), 256, 0, stream>>>(
      trigA + (size_t)2048 * 1024, 2048, -1022, 1, -1.f);
  trig_fill<<<dim3((1024 * 512 + 255) / 256), 256, 0, stream>>>(
      trigA + (size_t)4096 * 1024, 1024, -1022, 2, 1.f);
  trig_fill<<<dim3((1024 * 512 + 255) / 256), 256, 0, stream>>>(
      trigA + (size_t)5120 * 1024, 1024, -1020, 2, -1.f);
  trig_fill<<<dim3((512 * 512 + 255) / 256), 256, 0, stream>>>(
      trigA + (size_t)6144 * 1024, 512, -1020, 4, 1.f);

  const unsigned short* X = hA;

  for (int l = 11; l >= 0; --l) {
    int Lq, Lk, sq, sk, sqp, skp, nrel, rbase, troff;
    if (l <= 3)      { Lq=1024; Lk=1024; sq=1; sk=1; sqp=1; skp=1; nrel=2047; rbase=1023; troff=0; }
    else if (l == 4) { Lq=1024; Lk= 512; sq=1; sk=2; sqp=1; skp=2; nrel=2046; rbase=1022; troff=2048; }
    else if (l <= 7) { Lq= 512; Lk= 512; sq=2; sk=2; sqp=1; skp=1; nrel=1023; rbase= 511; troff=4096; }
    else if (l == 8) { Lq= 512; Lk= 256; sq=2; sk=4; sqp=1; skp=2; nrel=1022; rbase= 510; troff=5120; }
    else             { Lq= 256; Lk= 256; sq=4; sk=4; sqp=1; skp=1; nrel= 511; rbase= 255; troff=6144; }

    // block-entry upsample (reference order)
    if (l == 11) {
      const size_t total = (size_t)BATCH * 512 * DMODEL;
      upsample_k<<<dim3((unsigned)((total + 255) / 256)), 256, 0, stream>>>(
          X, upB, 256);
    } else if (l == 7) {
      const size_t total = (size_t)BATCH * 1024 * DMODEL;
      upsample_k<<<dim3((unsigned)((total + 255) / 256)), 256, 0, stream>>>(
          X, upB, 512);
    }
    const bool doUp = (l == 8) || (l == 4);
    const unsigned short* Xq = doUp ? upB : X;
    const int Mq = BATCH * Lq, Mk = BATCH * Lk;
    const int rPad = ((nrel + 127) / 128) * 128;

    // weight transposes (fp32 -> bf16 [n][k]) — one batched launch
    tpose5_k<<<dim3(32, 32, 5), 256, 0, stream>>>(
        Wq + (size_t)l * DMODEL * DMODEL, Wk + (size_t)l * DMODEL * DMODEL,
        Wv + (size_t)l * DMODEL * DMODEL, Wp + (size_t)l * DMODEL * DMODEL,
        rk + (size_t)l * DMODEL * DMODEL,
        wqkv, wqkv + (size_t)DMODEL * DMODEL, wqkv + (size_t)2 * DMODEL * DMODEL,
        wtp, rkT);

    // Wrel[head][r][h] (bf16) = sum_d rkT[head*64+h][d] * trig[r][d]
    gemm_bf16<3><<<dim3(DMODEL / 128, rPad / 128), 256, 0, stream>>>(
        rkT, trigA + (size_t)troff * 1024, nullptr, nullptr, wrelB,
        DMODEL, nrel, DMODEL, nrel);

    if (doUp) {
      gemm_bf16<1><<<dim3(Mq / 128, 8), 256, 0, stream>>>(
          Xq, wqkv, bq + l * DMODEL, nullptr, qB, Mq, DMODEL, DMODEL, 0);
      gemm_qkv<<<dim3(Mk / 128, 16), 256, 0, stream>>>(
          X, wqkv, bq + l * DMODEL, bk + l * DMODEL, bvv + l * DMODEL,
          qB, kBf, vBf, Mk, DMODEL, 1024);
    } else {
      gemm_qkv<<<dim3(Mq / 128, 24), 256, 0, stream>>>(
          X, wqkv, bq + l * DMODEL, bk + l * DMODEL, bvv + l * DMODEL,
          qB, kBf, vBf, Mq, DMODEL, 0);
    }

    dim3 ag(Lq / 64, NHEAD, BATCH);
    if (skp == 1)
      attn_mfma<64><<<ag, 256, 0, stream>>>(qB, kBf, vBf, wrelB,
          rw + l * NHEAD * 64, rr + l * NHEAD * 64, rs + l * NHEAD * 64,
          seg + l * 2 * NHEAD * 64, ids, vecB,
          Lq, Lk, sq, sk, sqp, skp, rbase, nrel);
    else
      attn_mfma<32><<<ag, 256, 0, stream>>>(qB, kBf, vBf, wrelB,
          rw + l * NHEAD * 64, rr + l * NHEAD * 64, rs + l * NHEAD * 64,
          seg + l * 2 * NHEAD * 64, ids, vecB,
          Lq, Lk, sq, sk, sqp, skp, rbase, nrel);

    // post projection + residual
    gemm_bf16<2><<<dim3(Mq / 128, 8), 256, 0, stream>>>(
        vecB, wtp, bp + l * DMODEL, Xq, pB, Mq, DMODEL, DMODEL, 0);
    if (l == 0) {
      ln_k<false><<<dim3(Mq), 256, 0, stream>>>(
          pB, lng + l * DMODEL, lnb + l * DMODEL, d_out);
    } else {
      unsigned short* outBuf = (X == hA) ? hB : hA;
      ln_k<true><<<dim3(Mq), 256, 0, stream>>>(
          pB, lng + l * DMODEL, lnb + l * DMODEL, outBuf);
      X = outBuf;
    }
  }
  (void)in_sizes; (void)n_in; (void)out_size; (void)ws_size;
}